// Round 3
// baseline (5164.970 us; speedup 1.0000x reference)
//
#include <hip/hip_runtime.h>
#include <math.h>

// MAGNN ctr_ntype: fused gather+GRU+attention+segment-sum, MFMA bf16.
// R3: runtime dtype sniffer (f32 vs bf16 input bytes) steering dual-path
// loads/stores; compute pipeline (MFMA bf16, layouts m89/m91/m120) unchanged.
// A[m=lane&15][k=quad*8+j], B[k=quad*8+j][n=lane&15], C/D col=lane&15,row=quad*4+reg.

typedef unsigned short u16;
typedef unsigned int u32;
typedef __bf16 bf16x8 __attribute__((ext_vector_type(8)));
typedef short short8 __attribute__((ext_vector_type(8)));
typedef float f32x4 __attribute__((ext_vector_type(4)));

#define N_NODES 20000
#define P_META 3
#define E_EDGES 60000
#define L_STEPS 4
#define DMODEL 256
#define G3 768
#define M_TILE 64
#define RS 264            // padded LDS row stride (u16): 16B-aligned rows, 2-way bank alias only (free, m136)
#define TILES_PER_P 938   // ceil(60000/64)

__device__ __forceinline__ float bf2f(u16 b) {
  u32 u = ((u32)b) << 16; float f; __builtin_memcpy(&f, &u, 4); return f;
}
__device__ __forceinline__ u16 f2bf(float f) {
  u32 u; __builtin_memcpy(&u, &f, 4);
  return (u16)((u + 0x7FFFu + ((u >> 16) & 1u)) >> 16);   // RNE
}

// load 8 consecutive float elements (either bf16 or f32 storage) as bf16 bits
__device__ __forceinline__ short8 load8(const void* base, int isbf, size_t off) {
  if (isbf) {
    return *(const short8*)((const u16*)base + off);
  } else {
    const float* f = (const float*)base + off;
    const float4 a = *(const float4*)f;
    const float4 b = *(const float4*)(f + 4);
    short8 r;
    r[0] = (short)f2bf(a.x); r[1] = (short)f2bf(a.y);
    r[2] = (short)f2bf(a.z); r[3] = (short)f2bf(a.w);
    r[4] = (short)f2bf(b.x); r[5] = (short)f2bf(b.y);
    r[6] = (short)f2bf(b.z); r[7] = (short)f2bf(b.w);
    return r;
  }
}
__device__ __forceinline__ float loadS(const void* base, int isbf, size_t off) {
  return isbf ? bf2f(((const u16*)base)[off]) : ((const float*)base)[off];
}

static __device__ __forceinline__ f32x4 mfma16(short8 a, short8 b, f32x4 c) {
  return __builtin_amdgcn_mfma_f32_16x16x32_bf16(
      __builtin_bit_cast(bf16x8, a), __builtin_bit_cast(bf16x8, b), c, 0, 0, 0);
}

// Decide input storage dtype from the first 256 bytes of `features`.
// bf16 data: even halfwords are sane bf16 (exp in [103,143] for N(0,1)).
// f32 data: even halfwords = low mantissa bits -> uniform random exponent.
__global__ void sniff_kernel(const void* __restrict__ feat, int* __restrict__ flag) {
  const int i = threadIdx.x;     // 0..63
  const u16 e = ((const u16*)feat)[2 * i];
  const int ex = (e >> 7) & 0xFF;
  const bool sane = (e == 0) || (ex >= 103 && ex <= 143);
  const unsigned long long b = __ballot(sane);
  if (i == 0) *flag = (__popcll(b) >= 32) ? 1 : 0;   // 1 = bf16, 0 = f32
}

__global__ __launch_bounds__(256, 1) void gru_edge_kernel(
    const void* __restrict__ features,   // [N,256]
    const void* __restrict__ w_ih,       // [P,768,256]
    const void* __restrict__ w_hh,       // [P,768,256]
    const void* __restrict__ b_ih,       // [P,768]
    const void* __restrict__ b_hh,       // [P,768]
    const int*  __restrict__ emi,        // [P,E,L]
    const int*  __restrict__ edst,       // [P,E]
    float*      __restrict__ nft,        // [P,N,256] fp32 accumulators (pre-zeroed)
    const int*  __restrict__ dflag)
{
  __shared__ u16 Hbuf[M_TILE * RS];     // 33,792 B
  __shared__ u16 Wst[96 * RS];          // 50,688 B

  const int isbf = *dflag;
  const int tid  = threadIdx.x;
  const int bx   = blockIdx.x;
  const int p    = bx / TILES_PER_P;
  const int tile = bx - p * TILES_PER_P;
  const int e0   = tile * M_TILE;
  const int wv   = tid >> 6;
  const int ln   = tid & 63;
  const int n16  = ln & 15;
  const int quad = ln >> 4;

  for (int i = tid; i < M_TILE * RS; i += 256) Hbuf[i] = 0;   // h0 = 0

  const int arow = wv * 16 + n16;
  int ea = e0 + arow; if (ea >= E_EDGES) ea = E_EDGES - 1;

  for (int step = 0; step < L_STEPS; ++step) {
    __syncthreads();  // prev step's h writes (and zero-init) complete
    short8 xf[8], hf[8];
    {
      const int fidx = emi[((size_t)p * E_EDGES + ea) * L_STEPS + step];
      const size_t xo = (size_t)fidx * DMODEL + quad * 8;
      const u16* hr = Hbuf + (size_t)arow * RS + quad * 8;
      #pragma unroll
      for (int k0 = 0; k0 < 8; ++k0) {
        xf[k0] = load8(features, isbf, xo + k0 * 32);
        hf[k0] = *(const short8*)(hr + k0 * 32);
      }
    }
    for (int c = 0; c < 16; ++c) {
      const int jb = c * 16;
      __syncthreads();  // all waves done reading prev Wst + done loading hf
      for (int i = tid; i < 3072; i += 256) {
        const int rw = i >> 5, ck = i & 31;
        const int mi = rw >> 4, nn = rw & 15;   // mi 0..2 = ih r/z/n, 3..5 = hh r/z/n
        const int mat = (mi >= 3) ? 1 : 0;
        const int g = mi - 3 * mat;
        const void* W = mat ? w_hh : w_ih;
        const size_t off = ((size_t)p * G3 + g * 256 + jb + nn) * DMODEL + ck * 8;
        *(short8*)(Wst + (size_t)rw * RS + ck * 8) = load8(W, isbf, off);
      }
      __syncthreads();
      f32x4 air = {0,0,0,0}, aiz = {0,0,0,0}, ain = {0,0,0,0};
      f32x4 ahr = {0,0,0,0}, ahz = {0,0,0,0}, ahn = {0,0,0,0};
      #pragma unroll
      for (int k0 = 0; k0 < 8; ++k0) {
        const u16* bp = Wst + (size_t)n16 * RS + k0 * 32 + quad * 8;
        short8 bir = *(const short8*)(bp);
        short8 biz = *(const short8*)(bp + 16 * RS);
        short8 bin = *(const short8*)(bp + 32 * RS);
        short8 bhr = *(const short8*)(bp + 48 * RS);
        short8 bhz = *(const short8*)(bp + 64 * RS);
        short8 bhn = *(const short8*)(bp + 80 * RS);
        air = mfma16(xf[k0], bir, air);
        ahr = mfma16(hf[k0], bhr, ahr);
        aiz = mfma16(xf[k0], biz, aiz);
        ahz = mfma16(hf[k0], bhz, ahz);
        ain = mfma16(xf[k0], bin, ain);
        ahn = mfma16(hf[k0], bhn, ahn);
      }
      const int j = jb + n16;
      const float bir_s = loadS(b_ih, isbf, (size_t)p * G3 + j);
      const float biz_s = loadS(b_ih, isbf, (size_t)p * G3 + 256 + j);
      const float bin_s = loadS(b_ih, isbf, (size_t)p * G3 + 512 + j);
      const float bhr_s = loadS(b_hh, isbf, (size_t)p * G3 + j);
      const float bhz_s = loadS(b_hh, isbf, (size_t)p * G3 + 256 + j);
      const float bhn_s = loadS(b_hh, isbf, (size_t)p * G3 + 512 + j);
      #pragma unroll
      for (int i = 0; i < 4; ++i) {
        const int m = wv * 16 + quad * 4 + i;
        const float rg = 1.0f / (1.0f + __expf(-((air[i] + bir_s) + (ahr[i] + bhr_s))));
        const float zg = 1.0f / (1.0f + __expf(-((aiz[i] + biz_s) + (ahz[i] + bhz_s))));
        const float ng = tanhf((ain[i] + bin_s) + rg * (ahn[i] + bhn_s));
        const float hold = bf2f(Hbuf[(size_t)m * RS + j]);
        Hbuf[(size_t)m * RS + j] = f2bf((1.0f - zg) * ng + zg * hold);
      }
    }
  }
  __syncthreads();

  // epilogue: head-norm (axis=H), sim vs normalized ft[dst], softmax(8 heads), segment-sum
  const int m = tid >> 2, q = tid & 3;   // 4 threads/edge, thread q owns dd in [q*8,q*8+8)
  const int e = e0 + m;
  const bool valid = (e < E_EDGES);
  const int ec = valid ? e : (E_EDGES - 1);
  const int dstn = edst[(size_t)p * E_EDGES + ec];
  const size_t fo = (size_t)dstn * DMODEL;

  float invh[8], invf[8];
  #pragma unroll
  for (int t2 = 0; t2 < 8; ++t2) {
    const int dd = q * 8 + t2;
    float sh = 0.f, sf = 0.f;
    #pragma unroll
    for (int hh = 0; hh < 8; ++hh) {
      const float hv = bf2f(Hbuf[(size_t)m * RS + hh * 32 + dd]);
      const float fv = loadS(features, isbf, fo + hh * 32 + dd);
      sh += hv * hv; sf += fv * fv;
    }
    invh[t2] = 1.0f / fmaxf(sqrtf(sh), 1e-12f);
    invf[t2] = 1.0f / fmaxf(sqrtf(sf), 1e-12f);
  }
  float sim[8];
  #pragma unroll
  for (int hh = 0; hh < 8; ++hh) {
    float s = 0.f;
    #pragma unroll
    for (int t2 = 0; t2 < 8; ++t2) {
      const int dd = q * 8 + t2;
      s += (bf2f(Hbuf[(size_t)m * RS + hh * 32 + dd]) * invh[t2]) *
           (loadS(features, isbf, fo + hh * 32 + dd) * invf[t2]);
    }
    sim[hh] = s;
  }
  #pragma unroll
  for (int hh = 0; hh < 8; ++hh) {
    sim[hh] += __shfl_xor(sim[hh], 1, 64);
    sim[hh] += __shfl_xor(sim[hh], 2, 64);
  }
  float mx = sim[0];
  #pragma unroll
  for (int hh = 1; hh < 8; ++hh) mx = fmaxf(mx, sim[hh]);
  float aw[8], se = 0.f;
  #pragma unroll
  for (int hh = 0; hh < 8; ++hh) { aw[hh] = __expf(sim[hh] - mx); se += aw[hh]; }
  const float sinv = 1.0f / se;
  if (valid) {
    float* outp = nft + ((size_t)p * N_NODES + dstn) * DMODEL;
    #pragma unroll
    for (int hh = 0; hh < 8; ++hh) {
      const float a = aw[hh] * sinv;
      #pragma unroll
      for (int t2 = 0; t2 < 8; ++t2) {
        const int dd = q * 8 + t2;
        const float ef = bf2f(Hbuf[(size_t)m * RS + hh * 32 + dd]) * invh[t2];
        atomicAdd(outp + hh * 32 + dd, ef * a);
      }
    }
  }
}

__global__ void semantic_score_kernel(const float* __restrict__ nft,
                                      const void* __restrict__ fc1,   // [32,32]
                                      const void* __restrict__ fc2,   // [8,32]
                                      float* __restrict__ s_out,
                                      const int* __restrict__ dflag) {
  __shared__ float fc1s[32 * 32];
  __shared__ float fc2s[8 * 32];
  __shared__ float red[4];
  const int isbf = *dflag;
  const int tid = threadIdx.x;
  for (int i = tid; i < 1024; i += 256) fc1s[i] = loadS(fc1, isbf, i);
  for (int i = tid; i < 256; i += 256) fc2s[i] = loadS(fc2, isbf, i);
  __syncthreads();
  const int p = blockIdx.y;
  const int g = blockIdx.x * 256 + tid;      // [0, 160000)
  const int n = g >> 3, hh = g & 7;
  const float* hrow = nft + ((size_t)p * N_NODES + n) * DMODEL + hh * 32;
  float hv[32];
  #pragma unroll
  for (int d4 = 0; d4 < 8; ++d4) {
    const float4 v = *(const float4*)(hrow + d4 * 4);
    hv[d4 * 4 + 0] = v.x; hv[d4 * 4 + 1] = v.y; hv[d4 * 4 + 2] = v.z; hv[d4 * 4 + 3] = v.w;
  }
  float acc = 0.f;
  for (int e = 0; e < 32; ++e) {
    float t = 0.f;
    #pragma unroll
    for (int d = 0; d < 32; ++d) t += hv[d] * fc1s[e * 32 + d];
    acc += tanhf(t) * fc2s[hh * 32 + e];
  }
  #pragma unroll
  for (int o = 32; o > 0; o >>= 1) acc += __shfl_xor(acc, o, 64);
  if ((tid & 63) == 0) red[tid >> 6] = acc;
  __syncthreads();
  if (tid == 0) atomicAdd(&s_out[p], red[0] + red[1] + red[2] + red[3]);
}

__global__ void combine_kernel(const float* __restrict__ nft,
                               const float* __restrict__ s_in,
                               void* __restrict__ out,
                               const int* __restrict__ dflag) {
  const int isbf = *dflag;
  const float inv_n = 1.0f / (float)N_NODES;
  const float s0 = s_in[0] * inv_n, s1 = s_in[1] * inv_n, s2 = s_in[2] * inv_n;
  const float mx = fmaxf(s0, fmaxf(s1, s2));
  const float x0 = __expf(s0 - mx), x1 = __expf(s1 - mx), x2 = __expf(s2 - mx);
  const float inv = 1.0f / (x0 + x1 + x2);
  const float w0 = x0 * inv, w1 = x1 * inv, w2 = x2 * inv;
  const size_t stride = (size_t)N_NODES * DMODEL;
  const size_t idx = ((size_t)blockIdx.x * 256 + threadIdx.x) * 4;
  if (idx >= stride) return;
  const float4 a = *(const float4*)(nft + idx);
  const float4 b = *(const float4*)(nft + stride + idx);
  const float4 c = *(const float4*)(nft + 2 * stride + idx);
  const float o0 = w0 * a.x + w1 * b.x + w2 * c.x;
  const float o1 = w0 * a.y + w1 * b.y + w2 * c.y;
  const float o2 = w0 * a.z + w1 * b.z + w2 * c.z;
  const float o3 = w0 * a.w + w1 * b.w + w2 * c.w;
  if (isbf) {
    ushort4 r; r.x = f2bf(o0); r.y = f2bf(o1); r.z = f2bf(o2); r.w = f2bf(o3);
    *(ushort4*)((u16*)out + idx) = r;
  } else {
    float4 r; r.x = o0; r.y = o1; r.z = o2; r.w = o3;
    *(float4*)((float*)out + idx) = r;
  }
}

// diagnostic: ws too small -> fill out with 0.125 pattern
__global__ void fill_diag_kernel(u16* __restrict__ out, int n) {
  int i = (blockIdx.x * 256 + threadIdx.x) * 8;
  if (i + 8 <= n) {
    const int v = 0x3E003E00;
    int4 w; w.x = v; w.y = v; w.z = v; w.w = v;
    *(int4*)(out + i) = w;
  } else {
    for (; i < n; ++i) out[i] = 0x3E00;
  }
}

extern "C" void kernel_launch(void* const* d_in, const int* in_sizes, int n_in,
                              void* d_out, int out_size, void* d_ws, size_t ws_size,
                              hipStream_t stream) {
  const void* features = d_in[0];
  const void* w_ih     = d_in[1];
  const void* w_hh     = d_in[2];
  const void* b_ih     = d_in[3];
  const void* b_hh     = d_in[4];
  const void* fc1      = d_in[5];
  const void* fc2      = d_in[6];
  const int*  emi      = (const int*)d_in[7];
  const int*  edst     = (const int*)d_in[8];

  const size_t NEED = ((size_t)P_META * N_NODES * DMODEL + 4) * sizeof(float);
  if (ws_size < NEED) {   // constant across calls -> graph-safe
    fill_diag_kernel<<<dim3((out_size / 8 + 255) / 256), 256, 0, stream>>>((u16*)d_out, out_size);
    return;
  }

  float* nft  = (float*)d_ws;                                   // [3,20000,256] fp32
  float* s_ws = nft + (size_t)P_META * N_NODES * DMODEL;        // [3] fp32
  int*   flag = (int*)(s_ws + 3);                               // dtype flag (inside NEED)

  hipMemsetAsync(d_ws, 0, NEED, stream);
  sniff_kernel<<<1, 64, 0, stream>>>(features, flag);
  gru_edge_kernel<<<dim3(P_META * TILES_PER_P), 256, 0, stream>>>(
      features, w_ih, w_hh, b_ih, b_hh, emi, edst, nft, flag);
  semantic_score_kernel<<<dim3(625, 3), 256, 0, stream>>>(nft, fc1, fc2, s_ws, flag);
  combine_kernel<<<dim3(5000), 256, 0, stream>>>(nft, s_ws, d_out, flag);
}

// Round 4
// 1805.725 us; speedup vs baseline: 2.8603x; 2.8603x over previous
//
#include <hip/hip_runtime.h>
#include <math.h>

// MAGNN ctr_ntype R4: pre-packed bf16 weights (XOR-swizzled LDS image),
// bf16 features + precomputed head-norms, 80KB LDS -> 2 blocks/CU,
// vectorized epilogue. MFMA layouts per m89/m91/m120 (verified by R3 pass):
// A[m=lane&15][k=quad*8+j], B[k=quad*8+j][n=lane&15], C/D col=lane&15,row=quad*4+reg.

typedef unsigned short u16;
typedef unsigned int u32;
typedef __bf16 bf16x8 __attribute__((ext_vector_type(8)));
typedef short short8 __attribute__((ext_vector_type(8)));
typedef float f32x4 __attribute__((ext_vector_type(4)));

#define N_NODES 20000
#define P_META 3
#define E_EDGES 60000
#define L_STEPS 4
#define DMODEL 256
#define G3 768
#define M_TILE 64
#define TILES_PER_P 938   // ceil(60000/64)

__device__ __forceinline__ float bf2f(u16 b) {
  u32 u = ((u32)b) << 16; float f; __builtin_memcpy(&f, &u, 4); return f;
}
__device__ __forceinline__ u16 f2bf(float f) {
  u32 u; __builtin_memcpy(&u, &f, 4);
  return (u16)((u + 0x7FFFu + ((u >> 16) & 1u)) >> 16);   // RNE
}
__device__ __forceinline__ short8 load8(const void* base, int isbf, size_t off) {
  if (isbf) return *(const short8*)((const u16*)base + off);
  const float* f = (const float*)base + off;
  const float4 a = *(const float4*)f;
  const float4 b = *(const float4*)(f + 4);
  short8 r;
  r[0] = (short)f2bf(a.x); r[1] = (short)f2bf(a.y);
  r[2] = (short)f2bf(a.z); r[3] = (short)f2bf(a.w);
  r[4] = (short)f2bf(b.x); r[5] = (short)f2bf(b.y);
  r[6] = (short)f2bf(b.z); r[7] = (short)f2bf(b.w);
  return r;
}
__device__ __forceinline__ float loadS(const void* base, int isbf, size_t off) {
  return isbf ? bf2f(((const u16*)base)[off]) : ((const float*)base)[off];
}
static __device__ __forceinline__ f32x4 mfma16(short8 a, short8 b, f32x4 c) {
  return __builtin_amdgcn_mfma_f32_16x16x32_bf16(
      __builtin_bit_cast(bf16x8, a), __builtin_bit_cast(bf16x8, b), c, 0, 0, 0);
}
__device__ __forceinline__ float sigm(float x) { return 1.0f / (1.0f + __expf(-x)); }
__device__ __forceinline__ float ftanh(float x) { return 1.0f - 2.0f / (__expf(2.0f * x) + 1.0f); }

// ---- dtype sniffer (unchanged from R3, proven) ----
__global__ void sniff_kernel(const void* __restrict__ feat, int* __restrict__ flag) {
  const int i = threadIdx.x;
  const u16 e = ((const u16*)feat)[2 * i];
  const int ex = (e >> 7) & 0xFF;
  const bool sane = (e == 0) || (ex >= 103 && ex <= 143);
  const unsigned long long b = __ballot(sane);
  if (i == 0) *flag = (__popcll(b) >= 32) ? 1 : 0;   // 1 = bf16, 0 = f32
}

// ---- pack weights into XOR-swizzled LDS image: Wpk[p][c][rw][ck'] bf16 ----
// LDS image addr (u16): rw*256 + ((unit ^ (rw&7))<<3) + (ck&7), unit = ck>>3.
// rw = mi*16+nn; mi 0..2 = ih r/z/n, 3..5 = hh r/z/n; source col j = c*16+nn.
__global__ void pack_weights_kernel(const void* __restrict__ w_ih,
                                    const void* __restrict__ w_hh,
                                    u16* __restrict__ Wpk,
                                    const int* __restrict__ dflag) {
  const int isbf = *dflag;
  const int u = blockIdx.x * 256 + threadIdx.x;     // [0, 147456)
  const int tile = u / 3072;                        // p*16 + c
  const int r = u - tile * 3072;
  const int rw = r >> 5, un = r & 31;
  const int p = tile >> 4, c = tile & 15;
  const int mi = rw >> 4, nn = rw & 15;
  const void* W = (mi >= 3) ? w_hh : w_ih;
  const int g = (mi >= 3) ? mi - 3 : mi;
  const size_t src = ((size_t)p * G3 + g * 256 + c * 16 + nn) * DMODEL + un * 8;
  short8 v = load8(W, isbf, src);
  const size_t dst = (size_t)tile * 24576 + rw * 256 + ((size_t)(un ^ (rw & 7)) << 3);
  *(short8*)(Wpk + dst) = v;
}

// ---- pack features to bf16 + per-(n,d) inverse head-norms ----
__global__ void pack_feat_kernel(const void* __restrict__ features,
                                 u16* __restrict__ Fpk,
                                 float* __restrict__ invf,
                                 const int* __restrict__ dflag) {
  const int isbf = *dflag;
  const int n = blockIdx.x * 8 + (threadIdx.x >> 5);
  const int dd = threadIdx.x & 31;
  float v[8]; float ss = 0.f;
  #pragma unroll
  for (int hh = 0; hh < 8; ++hh) {
    v[hh] = loadS(features, isbf, (size_t)n * DMODEL + hh * 32 + dd);
    ss += v[hh] * v[hh];
  }
  invf[(size_t)n * 32 + dd] = 1.0f / fmaxf(sqrtf(ss), 1e-12f);
  #pragma unroll
  for (int hh = 0; hh < 8; ++hh)
    Fpk[(size_t)n * DMODEL + hh * 32 + dd] = f2bf(v[hh]);
}

// ---- pack biases to fp32 table bpk[p][6][256] (0..2 ih r/z/n, 3..5 hh) ----
__global__ void pack_bias_kernel(const void* __restrict__ b_ih,
                                 const void* __restrict__ b_hh,
                                 float* __restrict__ bpk,
                                 const int* __restrict__ dflag) {
  const int isbf = *dflag;
  const int g = blockIdx.x * 256 + threadIdx.x;   // [0, 4608)
  const int p = g / 1536, r = g - p * 1536;
  const int gi = r >> 8, j = r & 255;
  const float v = (gi < 3) ? loadS(b_ih, isbf, (size_t)p * G3 + gi * 256 + j)
                           : loadS(b_hh, isbf, (size_t)p * G3 + (gi - 3) * 256 + j);
  bpk[g] = v;
}

__global__ __launch_bounds__(256, 2) void gru_edge_kernel(
    const u16*  __restrict__ Fpk,        // [N,256] bf16
    const u16*  __restrict__ Wpk,        // [P,16,96,256] bf16, swizzled image
    const float* __restrict__ bpk,       // [P,6,256] fp32
    const float* __restrict__ invf,      // [N,32]
    const int*  __restrict__ emi,        // [P,E,L]
    const int*  __restrict__ edst,       // [P,E]
    float*      __restrict__ nft)        // [P,N,256] fp32 (pre-zeroed)
{
  __shared__ u16 Hbuf[M_TILE * 256];    // 32 KB, XOR-swizzled 16B units
  __shared__ u16 Wst[96 * 256];         // 48 KB, image copied from Wpk

  const int tid  = threadIdx.x;
  const int bx   = blockIdx.x;
  const int p    = bx / TILES_PER_P;
  const int tile = bx - p * TILES_PER_P;
  const int e0   = tile * M_TILE;
  const int wv   = tid >> 6;
  const int ln   = tid & 63;
  const int n16  = ln & 15;
  const int quad = ln >> 4;

  for (int i = tid; i < 2048; i += 256) *(short8*)(Hbuf + i * 8) = (short8)0;

  const int arow = wv * 16 + n16;
  int ea = e0 + arow; if (ea >= E_EDGES) ea = E_EDGES - 1;
  const int sw = n16 & 7;               // row-swizzle key for A/B reads

  for (int step = 0; step < L_STEPS; ++step) {
    __syncthreads();  // prev step's Hbuf writes (and zero-init) visible
    short8 xf[8], hf[8];
    {
      const int fidx = emi[((size_t)p * E_EDGES + ea) * L_STEPS + step];
      const u16* xr = Fpk + (size_t)fidx * DMODEL;
      #pragma unroll
      for (int k0 = 0; k0 < 8; ++k0) {
        xf[k0] = *(const short8*)(xr + k0 * 32 + quad * 8);
        hf[k0] = *(const short8*)(Hbuf + arow * 256 + (((k0 * 4 + quad) ^ sw) << 3));
      }
    }
    for (int c = 0; c < 16; ++c) {
      __syncthreads();  // prev Wst reads + hf loads complete
      {
        const u16* src = Wpk + (size_t)(p * 16 + c) * 24576 + tid * 8;
        u16* dst = Wst + tid * 8;
        #pragma unroll
        for (int it = 0; it < 12; ++it)
          *(short8*)(dst + it * 2048) = *(const short8*)(src + it * 2048);
      }
      __syncthreads();
      f32x4 air = {0,0,0,0}, aiz = {0,0,0,0}, ain = {0,0,0,0};
      f32x4 ahr = {0,0,0,0}, ahz = {0,0,0,0}, ahn = {0,0,0,0};
      #pragma unroll
      for (int k0 = 0; k0 < 8; ++k0) {
        const u16* bp = Wst + n16 * 256 + (((k0 * 4 + quad) ^ sw) << 3);
        short8 bir = *(const short8*)(bp);
        short8 biz = *(const short8*)(bp + 4096);
        short8 bin = *(const short8*)(bp + 8192);
        short8 bhr = *(const short8*)(bp + 12288);
        short8 bhz = *(const short8*)(bp + 16384);
        short8 bhn = *(const short8*)(bp + 20480);
        air = mfma16(xf[k0], bir, air);
        ahr = mfma16(hf[k0], bhr, ahr);
        aiz = mfma16(xf[k0], biz, aiz);
        ahz = mfma16(hf[k0], bhz, ahz);
        ain = mfma16(xf[k0], bin, ain);
        ahn = mfma16(hf[k0], bhn, ahn);
      }
      const int j = c * 16 + n16;
      const float* bb = bpk + (size_t)p * 1536 + j;
      const float bir_s = bb[0],    bhr_s = bb[768];
      const float biz_s = bb[256],  bhz_s = bb[1024];
      const float bin_s = bb[512],  bhn_s = bb[1280];
      const int ju = ((j >> 3) << 3);  // unit base *8 (pre-swizzle)
      #pragma unroll
      for (int i = 0; i < 4; ++i) {
        const int m = wv * 16 + quad * 4 + i;
        const float rg = sigm((air[i] + bir_s) + (ahr[i] + bhr_s));
        const float zg = sigm((aiz[i] + biz_s) + (ahz[i] + bhz_s));
        const float ng = ftanh((ain[i] + bin_s) + rg * (ahn[i] + bhn_s));
        const int idx = m * 256 + ((ju ^ ((m & 7) << 3))) + (j & 7);
        const float hold = bf2f(Hbuf[idx]);
        Hbuf[idx] = f2bf((1.0f - zg) * ng + zg * hold);
      }
    }
  }
  __syncthreads();

  // ---- epilogue: vectorized. 4 threads/edge; thread q owns dd in [q*8,q*8+8) ----
  const int m = tid >> 2, q = tid & 3;
  const int e = e0 + m;
  const bool valid = (e < E_EDGES);
  const int ec = valid ? e : (E_EDGES - 1);
  const int dstn = edst[(size_t)p * E_EDGES + ec];

  short8 hrow[8], fr[8];
  #pragma unroll
  for (int hh = 0; hh < 8; ++hh) {
    hrow[hh] = *(const short8*)(Hbuf + m * 256 + (((hh * 4 + q) ^ (m & 7)) << 3));
    fr[hh]   = *(const short8*)(Fpk + (size_t)dstn * DMODEL + hh * 32 + q * 8);
  }
  const float4 if0 = *(const float4*)(invf + (size_t)dstn * 32 + q * 8);
  const float4 if1 = *(const float4*)(invf + (size_t)dstn * 32 + q * 8 + 4);
  float invfv[8] = {if0.x, if0.y, if0.z, if0.w, if1.x, if1.y, if1.z, if1.w};

  float invh[8];
  #pragma unroll
  for (int t2 = 0; t2 < 8; ++t2) {
    float sh = 0.f;
    #pragma unroll
    for (int hh = 0; hh < 8; ++hh) {
      const float hv = bf2f((u16)hrow[hh][t2]);
      sh += hv * hv;
    }
    invh[t2] = 1.0f / fmaxf(sqrtf(sh), 1e-12f);
  }
  float sim[8];
  #pragma unroll
  for (int hh = 0; hh < 8; ++hh) {
    float s = 0.f;
    #pragma unroll
    for (int t2 = 0; t2 < 8; ++t2)
      s += (bf2f((u16)hrow[hh][t2]) * invh[t2]) * (bf2f((u16)fr[hh][t2]) * invfv[t2]);
    sim[hh] = s;
  }
  #pragma unroll
  for (int hh = 0; hh < 8; ++hh) {
    sim[hh] += __shfl_xor(sim[hh], 1, 64);
    sim[hh] += __shfl_xor(sim[hh], 2, 64);
  }
  float mx = sim[0];
  #pragma unroll
  for (int hh = 1; hh < 8; ++hh) mx = fmaxf(mx, sim[hh]);
  float aw[8], se = 0.f;
  #pragma unroll
  for (int hh = 0; hh < 8; ++hh) { aw[hh] = __expf(sim[hh] - mx); se += aw[hh]; }
  const float sinv = 1.0f / se;
  if (valid) {
    float* outp = nft + ((size_t)p * N_NODES + dstn) * DMODEL + q * 8;
    #pragma unroll
    for (int hh = 0; hh < 8; ++hh) {
      const float a = aw[hh] * sinv;
      #pragma unroll
      for (int t2 = 0; t2 < 8; ++t2) {
        const float ef = bf2f((u16)hrow[hh][t2]) * invh[t2];
        atomicAdd(outp + hh * 32 + t2, ef * a);
      }
    }
  }
}

__global__ void semantic_score_kernel(const float* __restrict__ nft,
                                      const void* __restrict__ fc1,
                                      const void* __restrict__ fc2,
                                      float* __restrict__ s_out,
                                      const int* __restrict__ dflag) {
  __shared__ float fc1s[32 * 32];
  __shared__ float fc2s[8 * 32];
  __shared__ float red[4];
  const int isbf = *dflag;
  const int tid = threadIdx.x;
  for (int i = tid; i < 1024; i += 256) fc1s[i] = loadS(fc1, isbf, i);
  for (int i = tid; i < 256; i += 256) fc2s[i] = loadS(fc2, isbf, i);
  __syncthreads();
  const int p = blockIdx.y;
  const int g = blockIdx.x * 256 + tid;      // [0, 160000)
  const int n = g >> 3, hh = g & 7;
  const float* hrow = nft + ((size_t)p * N_NODES + n) * DMODEL + hh * 32;
  float hv[32];
  #pragma unroll
  for (int d4 = 0; d4 < 8; ++d4) {
    const float4 v = *(const float4*)(hrow + d4 * 4);
    hv[d4 * 4 + 0] = v.x; hv[d4 * 4 + 1] = v.y; hv[d4 * 4 + 2] = v.z; hv[d4 * 4 + 3] = v.w;
  }
  float acc = 0.f;
  for (int e = 0; e < 32; ++e) {
    float t = 0.f;
    #pragma unroll
    for (int d = 0; d < 32; ++d) t += hv[d] * fc1s[e * 32 + d];
    acc += tanhf(t) * fc2s[hh * 32 + e];
  }
  #pragma unroll
  for (int o = 32; o > 0; o >>= 1) acc += __shfl_xor(acc, o, 64);
  if ((tid & 63) == 0) red[tid >> 6] = acc;
  __syncthreads();
  if (tid == 0) atomicAdd(&s_out[p], red[0] + red[1] + red[2] + red[3]);
}

__global__ void combine_kernel(const float* __restrict__ nft,
                               const float* __restrict__ s_in,
                               void* __restrict__ out,
                               const int* __restrict__ dflag) {
  const int isbf = *dflag;
  const float inv_n = 1.0f / (float)N_NODES;
  const float s0 = s_in[0] * inv_n, s1 = s_in[1] * inv_n, s2 = s_in[2] * inv_n;
  const float mx = fmaxf(s0, fmaxf(s1, s2));
  const float x0 = __expf(s0 - mx), x1 = __expf(s1 - mx), x2 = __expf(s2 - mx);
  const float inv = 1.0f / (x0 + x1 + x2);
  const float w0 = x0 * inv, w1 = x1 * inv, w2 = x2 * inv;
  const size_t stride = (size_t)N_NODES * DMODEL;
  const size_t idx = ((size_t)blockIdx.x * 256 + threadIdx.x) * 4;
  if (idx >= stride) return;
  const float4 a = *(const float4*)(nft + idx);
  const float4 b = *(const float4*)(nft + stride + idx);
  const float4 c = *(const float4*)(nft + 2 * stride + idx);
  const float o0 = w0 * a.x + w1 * b.x + w2 * c.x;
  const float o1 = w0 * a.y + w1 * b.y + w2 * c.y;
  const float o2 = w0 * a.z + w1 * b.z + w2 * c.z;
  const float o3 = w0 * a.w + w1 * b.w + w2 * c.w;
  if (isbf) {
    ushort4 r; r.x = f2bf(o0); r.y = f2bf(o1); r.z = f2bf(o2); r.w = f2bf(o3);
    *(ushort4*)((u16*)out + idx) = r;
  } else {
    float4 r; r.x = o0; r.y = o1; r.z = o2; r.w = o3;
    *(float4*)((float*)out + idx) = r;
  }
}

__global__ void fill_diag_kernel(u16* __restrict__ out, int n) {
  int i = (blockIdx.x * 256 + threadIdx.x) * 8;
  if (i + 8 <= n) {
    const int v = 0x3E003E00;
    int4 w; w.x = v; w.y = v; w.z = v; w.w = v;
    *(int4*)(out + i) = w;
  } else {
    for (; i < n; ++i) out[i] = 0x3E00;
  }
}

extern "C" void kernel_launch(void* const* d_in, const int* in_sizes, int n_in,
                              void* d_out, int out_size, void* d_ws, size_t ws_size,
                              hipStream_t stream) {
  const void* features = d_in[0];
  const void* w_ih     = d_in[1];
  const void* w_hh     = d_in[2];
  const void* b_ih     = d_in[3];
  const void* b_hh     = d_in[4];
  const void* fc1      = d_in[5];
  const void* fc2      = d_in[6];
  const int*  emi      = (const int*)d_in[7];
  const int*  edst     = (const int*)d_in[8];

  // ws layout (floats): nft[15,360,000] | s_ws[3] | flag[1] | pad[4] |
  //   Wpk (589,824 f as u16x2) | Fpk (2,560,000 f) | invf[640,000] | bpk[4,608]
  const size_t NFT_F   = (size_t)P_META * N_NODES * DMODEL;      // 15,360,000
  const size_t OFF_WPK = NFT_F + 8;                               // 16B aligned
  const size_t OFF_FPK = OFF_WPK + 589824;
  const size_t OFF_INV = OFF_FPK + 2560000;
  const size_t OFF_BPK = OFF_INV + 640000;
  const size_t TOTAL_F = OFF_BPK + 4608;
  const size_t NEED    = TOTAL_F * sizeof(float);

  if (ws_size < NEED) {   // constant across calls -> graph-safe
    fill_diag_kernel<<<dim3((out_size / 8 + 255) / 256), 256, 0, stream>>>((u16*)d_out, out_size);
    return;
  }

  float* wsf  = (float*)d_ws;
  float* nft  = wsf;
  float* s_ws = wsf + NFT_F;
  int*   flag = (int*)(wsf + NFT_F + 3);
  u16*   Wpk  = (u16*)(wsf + OFF_WPK);
  u16*   Fpk  = (u16*)(wsf + OFF_FPK);
  float* invf = wsf + OFF_INV;
  float* bpk  = wsf + OFF_BPK;

  hipMemsetAsync(d_ws, 0, (NFT_F + 8) * sizeof(float), stream);
  sniff_kernel<<<1, 64, 0, stream>>>(features, flag);
  pack_weights_kernel<<<dim3(576), 256, 0, stream>>>(w_ih, w_hh, Wpk, flag);
  pack_feat_kernel<<<dim3(2500), 256, 0, stream>>>(features, Fpk, invf, flag);
  pack_bias_kernel<<<dim3(18), 256, 0, stream>>>(b_ih, b_hh, bpk, flag);
  gru_edge_kernel<<<dim3(P_META * TILES_PER_P), 256, 0, stream>>>(
      Fpk, Wpk, bpk, invf, emi, edst, nft);
  semantic_score_kernel<<<dim3(625, 3), 256, 0, stream>>>(nft, fc1, fc2, s_ws, flag);
  combine_kernel<<<dim3(5000), 256, 0, stream>>>(nft, s_ws, d_out, flag);
}

// Round 5
// 1297.170 us; speedup vs baseline: 3.9817x; 1.3920x over previous
//
#include <hip/hip_runtime.h>
#include <math.h>

// MAGNN ctr_ntype R5: B-fragments streamed from L2 (fragment-major Wpk),
// wave = column-subset (4 c-tiles x all 64 edges), no Wst, 2 barriers/step.
// MFMA 16x16x32 bf16, layouts (R3/R4-verified): A[m=lane&15][k=quad*8+j],
// B[k=quad*8+j][n=lane&15], C/D col=lane&15, row=quad*4+reg.

typedef unsigned short u16;
typedef unsigned int u32;
typedef __bf16 bf16x8 __attribute__((ext_vector_type(8)));
typedef short short8 __attribute__((ext_vector_type(8)));
typedef float f32x4 __attribute__((ext_vector_type(4)));

#define N_NODES 20000
#define P_META 3
#define E_EDGES 60000
#define L_STEPS 4
#define DMODEL 256
#define G3 768
#define M_TILE 64
#define TILES_PER_P 938   // ceil(60000/64)

__device__ __forceinline__ float bf2f(u16 b) {
  u32 u = ((u32)b) << 16; float f; __builtin_memcpy(&f, &u, 4); return f;
}
__device__ __forceinline__ u16 f2bf(float f) {
  u32 u; __builtin_memcpy(&u, &f, 4);
  return (u16)((u + 0x7FFFu + ((u >> 16) & 1u)) >> 16);   // RNE
}
__device__ __forceinline__ short8 load8(const void* base, int isbf, size_t off) {
  if (isbf) return *(const short8*)((const u16*)base + off);
  const float* f = (const float*)base + off;
  const float4 a = *(const float4*)f;
  const float4 b = *(const float4*)(f + 4);
  short8 r;
  r[0] = (short)f2bf(a.x); r[1] = (short)f2bf(a.y);
  r[2] = (short)f2bf(a.z); r[3] = (short)f2bf(a.w);
  r[4] = (short)f2bf(b.x); r[5] = (short)f2bf(b.y);
  r[6] = (short)f2bf(b.z); r[7] = (short)f2bf(b.w);
  return r;
}
__device__ __forceinline__ float loadS(const void* base, int isbf, size_t off) {
  return isbf ? bf2f(((const u16*)base)[off]) : ((const float*)base)[off];
}
static __device__ __forceinline__ f32x4 mfma16(short8 a, short8 b, f32x4 c) {
  return __builtin_amdgcn_mfma_f32_16x16x32_bf16(
      __builtin_bit_cast(bf16x8, a), __builtin_bit_cast(bf16x8, b), c, 0, 0, 0);
}
__device__ __forceinline__ float sigm(float x) { return 1.0f / (1.0f + __expf(-x)); }
__device__ __forceinline__ float ftanh(float x) { return 1.0f - 2.0f / (__expf(2.0f * x) + 1.0f); }

// ---- dtype sniffer (proven) ----
__global__ void sniff_kernel(const void* __restrict__ feat, int* __restrict__ flag) {
  const int i = threadIdx.x;
  const u16 e = ((const u16*)feat)[2 * i];
  const int ex = (e >> 7) & 0xFF;
  const bool sane = (e == 0) || (ex >= 103 && ex <= 143);
  const unsigned long long b = __ballot(sane);
  if (i == 0) *flag = (__popcll(b) >= 32) ? 1 : 0;   // 1 = bf16, 0 = f32
}

// ---- pack weights FRAGMENT-MAJOR: block fb = ((p*6+mat)*16+c)*8+k0, 1KB each;
// lane ln's 16B = W[col=c*16+(ln&15)][k = k0*32+(ln>>4)*8 + 0..7]. mat: 0..2 ih r/z/n, 3..5 hh.
__global__ void pack_weights_kernel(const void* __restrict__ w_ih,
                                    const void* __restrict__ w_hh,
                                    u16* __restrict__ Wpk,
                                    const int* __restrict__ dflag) {
  const int isbf = *dflag;
  const int g = blockIdx.x * 256 + threadIdx.x;     // [0, 147456)
  const int fb = g >> 6, ln = g & 63;
  const int k0 = fb & 7, c = (fb >> 3) & 15, pm = fb >> 7;   // pm = p*6+mat
  const int p = pm / 6, mat = pm - p * 6;
  const int gate = (mat >= 3) ? mat - 3 : mat;
  const void* W = (mat >= 3) ? w_hh : w_ih;
  const size_t src = ((size_t)p * G3 + gate * 256 + c * 16 + (ln & 15)) * DMODEL
                     + k0 * 32 + (ln >> 4) * 8;
  short8 v = load8(W, isbf, src);
  *(short8*)(Wpk + (size_t)fb * 512 + ln * 8) = v;
}

// ---- pack features to bf16 + per-(n,d) inverse head-norms (proven) ----
__global__ void pack_feat_kernel(const void* __restrict__ features,
                                 u16* __restrict__ Fpk,
                                 float* __restrict__ invf,
                                 const int* __restrict__ dflag) {
  const int isbf = *dflag;
  const int n = blockIdx.x * 8 + (threadIdx.x >> 5);
  const int dd = threadIdx.x & 31;
  float v[8]; float ss = 0.f;
  #pragma unroll
  for (int hh = 0; hh < 8; ++hh) {
    v[hh] = loadS(features, isbf, (size_t)n * DMODEL + hh * 32 + dd);
    ss += v[hh] * v[hh];
  }
  invf[(size_t)n * 32 + dd] = 1.0f / fmaxf(sqrtf(ss), 1e-12f);
  #pragma unroll
  for (int hh = 0; hh < 8; ++hh)
    Fpk[(size_t)n * DMODEL + hh * 32 + dd] = f2bf(v[hh]);
}

__global__ void pack_bias_kernel(const void* __restrict__ b_ih,
                                 const void* __restrict__ b_hh,
                                 float* __restrict__ bpk,
                                 const int* __restrict__ dflag) {
  const int isbf = *dflag;
  const int g = blockIdx.x * 256 + threadIdx.x;   // [0, 4608)
  const int p = g / 1536, r = g - p * 1536;
  const int gi = r >> 8, j = r & 255;
  const float v = (gi < 3) ? loadS(b_ih, isbf, (size_t)p * G3 + gi * 256 + j)
                           : loadS(b_hh, isbf, (size_t)p * G3 + (gi - 3) * 256 + j);
  bpk[g] = v;
}

__global__ __launch_bounds__(256, 2) void gru_edge_kernel(
    const u16*  __restrict__ Fpk,        // [N,256] bf16
    const u16*  __restrict__ Wpk,        // fragment-major, 2304 x 1KB
    const float* __restrict__ bpk,       // [P,6,256] fp32
    const float* __restrict__ invf,      // [N,32]
    const int*  __restrict__ emi,        // [P,E,L]
    const int*  __restrict__ edst,       // [P,E]
    float*      __restrict__ nft)        // [P,N,256] fp32 (pre-zeroed)
{
  __shared__ u16 Xbuf[64 * 256];        // 32 KB, XOR-swizzled 16B units
  __shared__ u16 Hbuf[64 * 256];        // 32 KB, same swizzle
  __shared__ float Bsh[1536];           // 6 KB bias slice

  const int tid  = threadIdx.x;
  const int bx   = blockIdx.x;
  const int p    = bx / TILES_PER_P;
  const int tile = bx - p * TILES_PER_P;
  const int e0   = tile * M_TILE;
  const int wv   = tid >> 6;
  const int ln   = tid & 63;
  const int n16  = ln & 15;
  const int quad = ln >> 4;
  const int cbase = wv * 4;             // this wave's 4 col-tiles

  for (int i = tid; i < 1536; i += 256) Bsh[i] = bpk[(size_t)p * 1536 + i];

  // gather assignment: 4 threads per edge
  const int m4 = tid >> 2, seg = tid & 3;
  int em4 = e0 + m4; if (em4 >= E_EDGES) em4 = E_EDGES - 1;
  const int swm = m4 & 7;

  u32 hn[32];   // packed bf16 h_new: v = ci*16+rt*4+i, pairs in u32

  for (int step = 0; step < L_STEPS; ++step) {
    // ---- gather X_t into Xbuf (swizzled) ----
    {
      const int fidx = emi[((size_t)p * E_EDGES + em4) * L_STEPS + step];
      const u16* frp = Fpk + (size_t)fidx * DMODEL;
      #pragma unroll
      for (int u = 0; u < 8; ++u) {
        short8 xv = *(const short8*)(frp + (seg * 8 + u) * 8);
        *(short8*)(Xbuf + m4 * 256 + (((seg * 8 + u) ^ swm) << 3)) = xv;
      }
    }
    __syncthreads();   // Xbuf ready; prev step's Hbuf writeback visible

    for (int ci = 0; ci < 4; ++ci) {
      const int c = cbase + ci;
      const f32x4 z4 = {0.f, 0.f, 0.f, 0.f};
      f32x4 aIR[4], aIZ[4], aIN[4], aHR[4], aHZ[4], aHN[4];
      #pragma unroll
      for (int rt = 0; rt < 4; ++rt) {
        aIR[rt] = z4; aIZ[rt] = z4; aIN[rt] = z4;
        aHR[rt] = z4; aHZ[rt] = z4; aHN[rt] = z4;
      }
      const u16* wb0 = Wpk + ((size_t)(p * 6 * 16 + c) * 8) * 512 + ln * 8;

      if (step == 0) {        // h0 = 0: ih mats only
        #pragma unroll 2
        for (int k0 = 0; k0 < 8; ++k0) {
          const int un = (((k0 * 4 + quad) ^ (n16 & 7)) << 3);
          const u16* xr = Xbuf + n16 * 256 + un;
          short8 x0 = *(const short8*)(xr);
          short8 x1 = *(const short8*)(xr + 4096);
          short8 x2 = *(const short8*)(xr + 8192);
          short8 x3 = *(const short8*)(xr + 12288);
          const u16* wk = wb0 + k0 * 512;
          short8 b0 = *(const short8*)(wk);
          short8 b1 = *(const short8*)(wk + 65536);
          short8 b2 = *(const short8*)(wk + 131072);
          aIR[0] = mfma16(x0, b0, aIR[0]); aIR[1] = mfma16(x1, b0, aIR[1]);
          aIR[2] = mfma16(x2, b0, aIR[2]); aIR[3] = mfma16(x3, b0, aIR[3]);
          aIZ[0] = mfma16(x0, b1, aIZ[0]); aIZ[1] = mfma16(x1, b1, aIZ[1]);
          aIZ[2] = mfma16(x2, b1, aIZ[2]); aIZ[3] = mfma16(x3, b1, aIZ[3]);
          aIN[0] = mfma16(x0, b2, aIN[0]); aIN[1] = mfma16(x1, b2, aIN[1]);
          aIN[2] = mfma16(x2, b2, aIN[2]); aIN[3] = mfma16(x3, b2, aIN[3]);
        }
      } else {
        #pragma unroll 2
        for (int k0 = 0; k0 < 8; ++k0) {
          const int un = (((k0 * 4 + quad) ^ (n16 & 7)) << 3);
          const u16* xr = Xbuf + n16 * 256 + un;
          const u16* hr = Hbuf + n16 * 256 + un;
          short8 x0 = *(const short8*)(xr);
          short8 x1 = *(const short8*)(xr + 4096);
          short8 x2 = *(const short8*)(xr + 8192);
          short8 x3 = *(const short8*)(xr + 12288);
          short8 h0 = *(const short8*)(hr);
          short8 h1 = *(const short8*)(hr + 4096);
          short8 h2 = *(const short8*)(hr + 8192);
          short8 h3 = *(const short8*)(hr + 12288);
          const u16* wk = wb0 + k0 * 512;
          short8 b0 = *(const short8*)(wk);
          short8 b1 = *(const short8*)(wk + 65536);
          short8 b2 = *(const short8*)(wk + 131072);
          short8 b3 = *(const short8*)(wk + 196608);
          short8 b4 = *(const short8*)(wk + 262144);
          short8 b5 = *(const short8*)(wk + 327680);
          aIR[0] = mfma16(x0, b0, aIR[0]); aIR[1] = mfma16(x1, b0, aIR[1]);
          aIR[2] = mfma16(x2, b0, aIR[2]); aIR[3] = mfma16(x3, b0, aIR[3]);
          aHR[0] = mfma16(h0, b3, aHR[0]); aHR[1] = mfma16(h1, b3, aHR[1]);
          aHR[2] = mfma16(h2, b3, aHR[2]); aHR[3] = mfma16(h3, b3, aHR[3]);
          aIZ[0] = mfma16(x0, b1, aIZ[0]); aIZ[1] = mfma16(x1, b1, aIZ[1]);
          aIZ[2] = mfma16(x2, b1, aIZ[2]); aIZ[3] = mfma16(x3, b1, aIZ[3]);
          aHZ[0] = mfma16(h0, b4, aHZ[0]); aHZ[1] = mfma16(h1, b4, aHZ[1]);
          aHZ[2] = mfma16(h2, b4, aHZ[2]); aHZ[3] = mfma16(h3, b4, aHZ[3]);
          aIN[0] = mfma16(x0, b2, aIN[0]); aIN[1] = mfma16(x1, b2, aIN[1]);
          aIN[2] = mfma16(x2, b2, aIN[2]); aIN[3] = mfma16(x3, b2, aIN[3]);
          aHN[0] = mfma16(h0, b5, aHN[0]); aHN[1] = mfma16(h1, b5, aHN[1]);
          aHN[2] = mfma16(h2, b5, aHN[2]); aHN[3] = mfma16(h3, b5, aHN[3]);
        }
      }
      // ---- gate math -> packed h_new regs ----
      const int j = c * 16 + n16;
      const float bir = Bsh[j],        bhr = Bsh[768 + j];
      const float biz = Bsh[256 + j],  bhz = Bsh[1024 + j];
      const float bin = Bsh[512 + j],  bhn = Bsh[1280 + j];
      const int ju = ((j >> 3) << 3), jl = j & 7;
      #pragma unroll
      for (int rt = 0; rt < 4; ++rt) {
        #pragma unroll
        for (int i = 0; i < 4; ++i) {
          const int mm = rt * 16 + quad * 4 + i;
          const float r = sigm((aIR[rt][i] + bir) + (aHR[rt][i] + bhr));
          const float z = sigm((aIZ[rt][i] + biz) + (aHZ[rt][i] + bhz));
          const float ng = ftanh((aIN[rt][i] + bin) + r * (aHN[rt][i] + bhn));
          float hold = 0.f;
          if (step > 0) hold = bf2f(Hbuf[mm * 256 + (ju ^ ((mm & 7) << 3)) + jl]);
          const u16 hb = f2bf((1.0f - z) * ng + z * hold);
          const int v = ci * 16 + rt * 4 + i;
          if (v & 1) hn[v >> 1] |= ((u32)hb) << 16;
          else       hn[v >> 1] = (u32)hb;
        }
      }
    }
    __syncthreads();   // all Xbuf/Hbuf reads for this step complete
    // ---- writeback h_new ----
    #pragma unroll
    for (int v = 0; v < 64; ++v) {
      const u16 hb = (v & 1) ? (u16)(hn[v >> 1] >> 16) : (u16)(hn[v >> 1] & 0xFFFFu);
      const int ci = v >> 4, rt = (v >> 2) & 3, i = v & 3;
      const int mm = rt * 16 + quad * 4 + i;
      const int j = (cbase + ci) * 16 + n16;
      Hbuf[mm * 256 + ((((j >> 3) ^ (mm & 7))) << 3) + (j & 7)] = hb;
    }
    // next iteration's post-gather barrier makes these writes visible
  }
  __syncthreads();   // final hidden in Hbuf, visible to all waves

  // ---- epilogue phase 1: norms + sim + softmax (R4-proven), results -> LDS ----
  const int m = tid >> 2, q = tid & 3;
  const int e = e0 + m;
  const int ec = (e < E_EDGES) ? e : (E_EDGES - 1);
  const int dstn = edst[(size_t)p * E_EDGES + ec];

  short8 hrow[8], fr[8];
  #pragma unroll
  for (int hh = 0; hh < 8; ++hh) {
    hrow[hh] = *(const short8*)(Hbuf + m * 256 + (((hh * 4 + q) ^ (m & 7)) << 3));
    fr[hh]   = *(const short8*)(Fpk + (size_t)dstn * DMODEL + hh * 32 + q * 8);
  }
  const float4 if0 = *(const float4*)(invf + (size_t)dstn * 32 + q * 8);
  const float4 if1 = *(const float4*)(invf + (size_t)dstn * 32 + q * 8 + 4);
  float invfv[8] = {if0.x, if0.y, if0.z, if0.w, if1.x, if1.y, if1.z, if1.w};

  float invh[8];
  #pragma unroll
  for (int t2 = 0; t2 < 8; ++t2) {
    float sh = 0.f;
    #pragma unroll
    for (int hh = 0; hh < 8; ++hh) {
      const float hv = bf2f((u16)hrow[hh][t2]);
      sh += hv * hv;
    }
    invh[t2] = 1.0f / fmaxf(sqrtf(sh), 1e-12f);
  }
  float sim[8];
  #pragma unroll
  for (int hh = 0; hh < 8; ++hh) {
    float s = 0.f;
    #pragma unroll
    for (int t2 = 0; t2 < 8; ++t2)
      s += (bf2f((u16)hrow[hh][t2]) * invh[t2]) * (bf2f((u16)fr[hh][t2]) * invfv[t2]);
    sim[hh] = s;
  }
  #pragma unroll
  for (int hh = 0; hh < 8; ++hh) {
    sim[hh] += __shfl_xor(sim[hh], 1, 64);
    sim[hh] += __shfl_xor(sim[hh], 2, 64);
  }
  float mx = sim[0];
  #pragma unroll
  for (int hh = 1; hh < 8; ++hh) mx = fmaxf(mx, sim[hh]);
  float aw[8], se = 0.f;
  #pragma unroll
  for (int hh = 0; hh < 8; ++hh) { aw[hh] = __expf(sim[hh] - mx); se += aw[hh]; }
  const float sinv = 1.0f / se;

  float* invhs = (float*)Xbuf;            // [64][32]
  float* aws   = ((float*)Xbuf) + 2048;   // [64][8]
  #pragma unroll
  for (int t2 = 0; t2 < 8; ++t2) invhs[m * 32 + q * 8 + t2] = invh[t2];
  if (q == 0) {
    #pragma unroll
    for (int hh = 0; hh < 8; ++hh) aws[m * 8 + hh] = aw[hh] * sinv;
  }
  __syncthreads();

  // ---- epilogue phase 2: line-merged atomics (16 lanes -> one 64B line) ----
  const int esub = ln >> 4;     // 0..3: edge within group of 4
  const int li   = ln & 15;     // dword within 64B line
  for (int pp = 0; pp < 4; ++pp) {
    const int em = wv * 16 + pp * 4 + esub;
    const int ee = e0 + em;
    if (ee < E_EDGES) {
      const int dn = edst[(size_t)p * E_EDGES + ee];
      float* op = nft + ((size_t)p * N_NODES + dn) * DMODEL;
      const float* ivh = invhs + em * 32;
      const float* awp = aws + em * 8;
      #pragma unroll
      for (int t = 0; t < 16; ++t) {
        const int idx = t * 16 + li;
        const u16 hb = Hbuf[em * 256 + ((((idx >> 3) ^ (em & 7))) << 3) + (idx & 7)];
        const float val = bf2f(hb) * ivh[idx & 31] * awp[idx >> 5];
        atomicAdd(op + idx, val);
      }
    }
  }
}

__global__ void semantic_score_kernel(const float* __restrict__ nft,
                                      const void* __restrict__ fc1,
                                      const void* __restrict__ fc2,
                                      float* __restrict__ s_out,
                                      const int* __restrict__ dflag) {
  __shared__ float fc1s[32 * 32];
  __shared__ float fc2s[8 * 32];
  __shared__ float red[4];
  const int isbf = *dflag;
  const int tid = threadIdx.x;
  for (int i = tid; i < 1024; i += 256) fc1s[i] = loadS(fc1, isbf, i);
  for (int i = tid; i < 256; i += 256) fc2s[i] = loadS(fc2, isbf, i);
  __syncthreads();
  const int p = blockIdx.y;
  const int g = blockIdx.x * 256 + tid;      // [0, 160000)
  const int n = g >> 3, hh = g & 7;
  const float* hrow = nft + ((size_t)p * N_NODES + n) * DMODEL + hh * 32;
  float hv[32];
  #pragma unroll
  for (int d4 = 0; d4 < 8; ++d4) {
    const float4 v = *(const float4*)(hrow + d4 * 4);
    hv[d4 * 4 + 0] = v.x; hv[d4 * 4 + 1] = v.y; hv[d4 * 4 + 2] = v.z; hv[d4 * 4 + 3] = v.w;
  }
  float acc = 0.f;
  for (int e = 0; e < 32; ++e) {
    float t = 0.f;
    #pragma unroll
    for (int d = 0; d < 32; ++d) t += hv[d] * fc1s[e * 32 + d];
    acc += tanhf(t) * fc2s[hh * 32 + e];
  }
  #pragma unroll
  for (int o = 32; o > 0; o >>= 1) acc += __shfl_xor(acc, o, 64);
  if ((tid & 63) == 0) red[tid >> 6] = acc;
  __syncthreads();
  if (tid == 0) atomicAdd(&s_out[p], red[0] + red[1] + red[2] + red[3]);
}

__global__ void combine_kernel(const float* __restrict__ nft,
                               const float* __restrict__ s_in,
                               void* __restrict__ out,
                               const int* __restrict__ dflag) {
  const int isbf = *dflag;
  const float inv_n = 1.0f / (float)N_NODES;
  const float s0 = s_in[0] * inv_n, s1 = s_in[1] * inv_n, s2 = s_in[2] * inv_n;
  const float mx = fmaxf(s0, fmaxf(s1, s2));
  const float x0 = __expf(s0 - mx), x1 = __expf(s1 - mx), x2 = __expf(s2 - mx);
  const float inv = 1.0f / (x0 + x1 + x2);
  const float w0 = x0 * inv, w1 = x1 * inv, w2 = x2 * inv;
  const size_t stride = (size_t)N_NODES * DMODEL;
  const size_t idx = ((size_t)blockIdx.x * 256 + threadIdx.x) * 4;
  if (idx >= stride) return;
  const float4 a = *(const float4*)(nft + idx);
  const float4 b = *(const float4*)(nft + stride + idx);
  const float4 c = *(const float4*)(nft + 2 * stride + idx);
  const float o0 = w0 * a.x + w1 * b.x + w2 * c.x;
  const float o1 = w0 * a.y + w1 * b.y + w2 * c.y;
  const float o2 = w0 * a.z + w1 * b.z + w2 * c.z;
  const float o3 = w0 * a.w + w1 * b.w + w2 * c.w;
  if (isbf) {
    ushort4 r; r.x = f2bf(o0); r.y = f2bf(o1); r.z = f2bf(o2); r.w = f2bf(o3);
    *(ushort4*)((u16*)out + idx) = r;
  } else {
    float4 r; r.x = o0; r.y = o1; r.z = o2; r.w = o3;
    *(float4*)((float*)out + idx) = r;
  }
}

__global__ void fill_diag_kernel(u16* __restrict__ out, int n) {
  int i = (blockIdx.x * 256 + threadIdx.x) * 8;
  if (i + 8 <= n) {
    const int v = 0x3E003E00;
    int4 w; w.x = v; w.y = v; w.z = v; w.w = v;
    *(int4*)(out + i) = w;
  } else {
    for (; i < n; ++i) out[i] = 0x3E00;
  }
}

extern "C" void kernel_launch(void* const* d_in, const int* in_sizes, int n_in,
                              void* d_out, int out_size, void* d_ws, size_t ws_size,
                              hipStream_t stream) {
  const void* features = d_in[0];
  const void* w_ih     = d_in[1];
  const void* w_hh     = d_in[2];
  const void* b_ih     = d_in[3];
  const void* b_hh     = d_in[4];
  const void* fc1      = d_in[5];
  const void* fc2      = d_in[6];
  const int*  emi      = (const int*)d_in[7];
  const int*  edst     = (const int*)d_in[8];

  const size_t NFT_F   = (size_t)P_META * N_NODES * DMODEL;      // 15,360,000
  const size_t OFF_WPK = NFT_F + 8;
  const size_t OFF_FPK = OFF_WPK + 589824;
  const size_t OFF_INV = OFF_FPK + 2560000;
  const size_t OFF_BPK = OFF_INV + 640000;
  const size_t TOTAL_F = OFF_BPK + 4608;
  const size_t NEED    = TOTAL_F * sizeof(float);

  if (ws_size < NEED) {   // constant across calls -> graph-safe
    fill_diag_kernel<<<dim3((out_size / 8 + 255) / 256), 256, 0, stream>>>((u16*)d_out, out_size);
    return;
  }

  float* wsf  = (float*)d_ws;
  float* nft  = wsf;
  float* s_ws = wsf + NFT_F;
  int*   flag = (int*)(wsf + NFT_F + 3);
  u16*   Wpk  = (u16*)(wsf + OFF_WPK);
  u16*   Fpk  = (u16*)(wsf + OFF_FPK);
  float* invf = wsf + OFF_INV;
  float* bpk  = wsf + OFF_BPK;

  hipMemsetAsync(d_ws, 0, (NFT_F + 8) * sizeof(float), stream);
  sniff_kernel<<<1, 64, 0, stream>>>(features, flag);
  pack_weights_kernel<<<dim3(576), 256, 0, stream>>>(w_ih, w_hh, Wpk, flag);
  pack_feat_kernel<<<dim3(2500), 256, 0, stream>>>(features, Fpk, invf, flag);
  pack_bias_kernel<<<dim3(18), 256, 0, stream>>>(b_ih, b_hh, bpk, flag);
  gru_edge_kernel<<<dim3(P_META * TILES_PER_P), 256, 0, stream>>>(
      Fpk, Wpk, bpk, invf, emi, edst, nft);
  semantic_score_kernel<<<dim3(625, 3), 256, 0, stream>>>(nft, fc1, fc2, s_ws, flag);
  combine_kernel<<<dim3(5000), 256, 0, stream>>>(nft, s_ws, d_out, flag);
}